// Round 4
// baseline (96.887 us; speedup 1.0000x reference)
//
#include <hip/hip_runtime.h>

// LIF scan, 2001 steps over 32768 fp32 neurons. Outputs (flat fp32 in d_out):
//   s_last [N], v_last [N], v_t [T*N], s_t [T*N];  N=32768, T=2001 -> 525 MB writes.
//
// HBM-write-bound. float4 (16B) stores need 4 neurons/thread; to keep all CUs
// busy, time is split into 16 chunks. Each block replays the recurrence
// (storeless) to its chunk start, then streams its chunk with 16B NT stores.
//
// CORRECTNESS-CRITICAL: contract(off). With hipcc's default -ffp-contract=fast
// the backend may fuse mul+add into v_fmac/v_pk_fma across the 4 unrolled
// chains, changing rounding -> spike-decision flips vs the mul-then-add numpy
// reference (round-2 failure: sparse absmax ~= THRESHOLD on v_t).
//
// NOTE: __builtin_nontemporal_store needs a clang vector type, not HIP's
// float4 struct -> use ext_vector_type(4) (round-3 compile fix).

#pragma clang fp contract(off)

typedef float f32x4 __attribute__((ext_vector_type(4)));

#define T_STEPS 2001
#define NCHUNK  16
#define CHUNK   126   // 15*126 = 1890; last chunk covers 111 steps

__global__ __launch_bounds__(256) void lif_chunk_kernel(
    const f32x4* __restrict__ x4,
    f32x4*  __restrict__ s_last4,
    f32x4*  __restrict__ v_last4,
    f32x4* __restrict__ v_t4,
    f32x4* __restrict__ s_t4,
    int n4)                      // n/4 = 8192
{
    #pragma clang fp contract(off)

    const float LEAK   = 0.95f;
    const float DRIVE  = 0.05f;  // same bits as float(1.0 - 0.95)
    const float THRESH = 0.3f;

    const int bid   = blockIdx.x;
    const int chunk = bid >> 5;               // 32 neuron-blocks per chunk
    const int nb    = bid & 31;
    const int tid   = nb * 256 + threadIdx.x; // [0, 8192): float4 lane index

    const f32x4 xv = x4[tid];
    f32x4 dr;
    dr.x = DRIVE * xv.x;   // bit-exact hoist: same product every step
    dr.y = DRIVE * xv.y;
    dr.z = DRIVE * xv.z;
    dr.w = DRIVE * xv.w;

    f32x4 v = (f32x4){0.f, 0.f, 0.f, 0.f};

    const int t0 = chunk * CHUNK;
    const int t1 = (t0 + CHUNK < T_STEPS) ? (t0 + CHUNK) : T_STEPS;

    // ---- replay (no stores) ----
    #pragma unroll 4
    for (int t = 0; t < t0; ++t) {
        v.x = LEAK * v.x + dr.x; v.x = (v.x > THRESH) ? 0.f : v.x;
        v.y = LEAK * v.y + dr.y; v.y = (v.y > THRESH) ? 0.f : v.y;
        v.z = LEAK * v.z + dr.z; v.z = (v.z > THRESH) ? 0.f : v.z;
        v.w = LEAK * v.w + dr.w; v.w = (v.w > THRESH) ? 0.f : v.w;
    }

    // ---- owned chunk: compute + 16B NT stores ----
    size_t off = (size_t)t0 * (size_t)n4 + (size_t)tid;
    f32x4 s = (f32x4){0.f, 0.f, 0.f, 0.f};

    #pragma unroll 2
    for (int t = t0; t < t1; ++t) {
        bool k;
        v.x = LEAK * v.x + dr.x; k = v.x > THRESH; v.x = k ? 0.f : v.x; s.x = k ? 1.f : 0.f;
        v.y = LEAK * v.y + dr.y; k = v.y > THRESH; v.y = k ? 0.f : v.y; s.y = k ? 1.f : 0.f;
        v.z = LEAK * v.z + dr.z; k = v.z > THRESH; v.z = k ? 0.f : v.z; s.z = k ? 1.f : 0.f;
        v.w = LEAK * v.w + dr.w; k = v.w > THRESH; v.w = k ? 0.f : v.w; s.w = k ? 1.f : 0.f;
        __builtin_nontemporal_store(v, &v_t4[off]);
        __builtin_nontemporal_store(s, &s_t4[off]);
        off += (size_t)n4;
    }

    if (chunk == NCHUNK - 1) {
        s_last4[tid] = s;   // s_t[-1]
        v_last4[tid] = v;   // final carry
    }
}

extern "C" void kernel_launch(void* const* d_in, const int* in_sizes, int n_in,
                              void* d_out, int out_size, void* d_ws, size_t ws_size,
                              hipStream_t stream)
{
    const float* x = (const float*)d_in[0];
    const int n  = in_sizes[0];          // 32768
    const int n4 = n / 4;                // 8192

    float* out    = (float*)d_out;
    float* s_last = out;
    float* v_last = out + n;
    float* v_t    = out + 2 * (size_t)n;
    float* s_t    = out + 2 * (size_t)n + (size_t)T_STEPS * (size_t)n;

    const int block = 256;
    const int grid  = (n4 / block) * NCHUNK;   // 32 * 16 = 512 blocks -> 2/CU
    lif_chunk_kernel<<<grid, block, 0, stream>>>(
        (const f32x4*)x, (f32x4*)s_last, (f32x4*)v_last,
        (f32x4*)v_t, (f32x4*)s_t, n4);
}

// Round 5
// 90.035 us; speedup vs baseline: 1.0761x; 1.0761x over previous
//
#include <hip/hip_runtime.h>

// LIF scan, 2001 steps over 32768 fp32 neurons. Outputs (flat fp32 in d_out):
//   s_last [N], v_last [N], v_t [T*N], s_t [T*N];  N=32768, T=2001 -> 525 MB writes.
//
// HBM-write-bound. 16B/lane stores need 4 neurons/thread; time is split into
// 16 chunks (512 blocks, 2/CU) so all CUs stay busy. Each block replays the
// recurrence (storeless, bit-exact) to its chunk start, then streams its chunk.
//
// Round-4 lesson: __builtin_nontemporal_store capped write BW at ~5.4 TB/s
// (vs 6.9 TB/s fill ceiling through L2) -> plain dwordx4 stores here.
// Round-2 lesson: default -ffp-contract=fast fuses mul+add -> spike flips.
//   Fix: contract(off) pragma AND explicit __fmul_rn/__fadd_rn (round-1-proven).

#pragma clang fp contract(off)

typedef float f32x4 __attribute__((ext_vector_type(4)));

#define T_STEPS 2001
#define NCHUNK  16
#define CHUNK   126   // 15*126 = 1890; last chunk covers 111 steps

__device__ __forceinline__ float lif_v_step(float v, float dr) {
    // v' = 0.95*v + dr, hard reset to 0 above threshold. Plain RN mul-then-add.
    float u = __fadd_rn(__fmul_rn(0.95f, v), dr);
    return (u > 0.3f) ? 0.f : u;
}

__global__ __launch_bounds__(256) void lif_chunk_kernel(
    const f32x4* __restrict__ x4,
    f32x4* __restrict__ s_last4,
    f32x4* __restrict__ v_last4,
    f32x4* __restrict__ v_t4,
    f32x4* __restrict__ s_t4,
    int n4)                      // n/4 = 8192
{
    #pragma clang fp contract(off)

    const int bid   = blockIdx.x;
    const int chunk = bid >> 5;               // 32 neuron-blocks per chunk
    const int nb    = bid & 31;
    const int tid   = nb * 256 + threadIdx.x; // [0, 8192): float4 lane index

    const f32x4 xv = x4[tid];
    f32x4 dr;
    dr.x = __fmul_rn(0.05f, xv.x);   // bit-exact hoist: same product every step
    dr.y = __fmul_rn(0.05f, xv.y);
    dr.z = __fmul_rn(0.05f, xv.z);
    dr.w = __fmul_rn(0.05f, xv.w);

    f32x4 v = (f32x4){0.f, 0.f, 0.f, 0.f};

    const int t0 = chunk * CHUNK;
    const int t1 = (t0 + CHUNK < T_STEPS) ? (t0 + CHUNK) : T_STEPS;

    // ---- replay (no stores) ----
    #pragma unroll 4
    for (int t = 0; t < t0; ++t) {
        v.x = lif_v_step(v.x, dr.x);
        v.y = lif_v_step(v.y, dr.y);
        v.z = lif_v_step(v.z, dr.z);
        v.w = lif_v_step(v.w, dr.w);
    }

    // ---- owned chunk: compute + plain 16B stores ----
    size_t off = (size_t)t0 * (size_t)n4 + (size_t)tid;
    f32x4 s = (f32x4){0.f, 0.f, 0.f, 0.f};

    #pragma unroll 2
    for (int t = t0; t < t1; ++t) {
        float u; bool k;
        u = __fadd_rn(__fmul_rn(0.95f, v.x), dr.x); k = u > 0.3f; v.x = k ? 0.f : u; s.x = k ? 1.f : 0.f;
        u = __fadd_rn(__fmul_rn(0.95f, v.y), dr.y); k = u > 0.3f; v.y = k ? 0.f : u; s.y = k ? 1.f : 0.f;
        u = __fadd_rn(__fmul_rn(0.95f, v.z), dr.z); k = u > 0.3f; v.z = k ? 0.f : u; s.z = k ? 1.f : 0.f;
        u = __fadd_rn(__fmul_rn(0.95f, v.w), dr.w); k = u > 0.3f; v.w = k ? 0.f : u; s.w = k ? 1.f : 0.f;
        v_t4[off] = v;
        s_t4[off] = s;
        off += (size_t)n4;
    }

    if (chunk == NCHUNK - 1) {
        s_last4[tid] = s;   // s_t[-1]
        v_last4[tid] = v;   // final carry
    }
}

extern "C" void kernel_launch(void* const* d_in, const int* in_sizes, int n_in,
                              void* d_out, int out_size, void* d_ws, size_t ws_size,
                              hipStream_t stream)
{
    const float* x = (const float*)d_in[0];
    const int n  = in_sizes[0];          // 32768
    const int n4 = n / 4;                // 8192

    float* out    = (float*)d_out;
    float* s_last = out;
    float* v_last = out + n;
    float* v_t    = out + 2 * (size_t)n;
    float* s_t    = out + 2 * (size_t)n + (size_t)T_STEPS * (size_t)n;

    const int block = 256;
    const int grid  = (n4 / block) * NCHUNK;   // 32 * 16 = 512 blocks -> 2/CU
    lif_chunk_kernel<<<grid, block, 0, stream>>>(
        (const f32x4*)x, (f32x4*)s_last, (f32x4*)v_last,
        (f32x4*)v_t, (f32x4*)s_t, n4);
}